// Round 5
// baseline (113.724 us; speedup 1.0000x reference)
//
#include <hip/hip_runtime.h>

#define ALPHA 0.2f
#define LOG2E 1.44269504088896340736f

constexpr int BB  = 4;
constexpr int NN  = 2048;
constexpr int FIN = 128;
constexpr int FO  = 64;
constexpr int HH  = 4;
constexpr int CC  = BB * HH;   // 16 (b,h) combos

using half8   = __attribute__((ext_vector_type(8))) _Float16;
using floatx4 = __attribute__((ext_vector_type(4))) float;

__device__ __forceinline__ float fast_exp2(float x) {
#if __has_builtin(__builtin_amdgcn_exp2f)
  return __builtin_amdgcn_exp2f(x);
#else
  return exp2f(x);
#endif
}

union PK4 { _Float16 f[4]; uint2 u; };

// ---------------------------------------------------------------------------
// K12: two block roles in one kernel.
//  blocks 0..511   : adjacency bitpack (HBM-streaming; launched first so its
//                    16 MB adj read overlaps projection compute).
//  blocks 512..1023: projection ht = h·W via f16 MFMA; esrc/edst via
//                    associativity h·(W·a) fp32-exact (log2e-scaled);
//                    per-(c,tile) edst max -> gpart. XCD-pinned: block for c
//                    lands on XCD c&7 (same pin as K3's readers -> htT[c]
//                    written into the home L2 K3 will read from).
// grid 1024 x 256.
// ---------------------------------------------------------------------------
__global__ __launch_bounds__(256) void gat_k12(
    const float* __restrict__ h, const float* __restrict__ W,
    const float* __restrict__ a, const float* __restrict__ adj,
    _Float16* __restrict__ htT, float* __restrict__ esrcT,
    float* __restrict__ edst, float* __restrict__ gpart,
    unsigned* __restrict__ adjbits) {
  const int blk = blockIdx.x;
  const int t = threadIdx.x;
  const int w = t >> 6, lane = t & 63;

  if (blk < 512) {
    // ---------------- role A: adjacency bitpack ----------------
    const int m = blk * 4 + w;
    float areg[32];
    const float* arow = adj + (size_t)m * NN;
#pragma unroll
    for (int j = 0; j < 32; ++j) areg[j] = arow[j * 64 + lane];
#pragma unroll
    for (int j = 0; j < 32; ++j) {
      const unsigned long long mask = __ballot(areg[j] != 0.f);
      if (lane == 0) {
        adjbits[m * 64 + j * 2 + 0] = (unsigned)mask;
        adjbits[m * 64 + j * 2 + 1] = (unsigned)(mask >> 32);
      }
    }
    return;
  }

  // ---------------- role B: projection ----------------
  const int pb = blk - 512;
  const int c  = (pb & 7) | (((pb >> 3) & 1) << 3);  // XCD pin: pb%8 == c&7
  const int nt = pb >> 4;
  const int n0 = nt * 64;
  const int b = c >> 2, hh = c & 3;
  const int q = lane >> 4, r16 = lane & 15;

  __shared__ __align__(16) _Float16 Xs[64 * 128];   // 16 KB swizzled h-tile
  __shared__ __align__(16) _Float16 WT[64 * 128];   // 16 KB swizzled W^T
  __shared__ float wasb[128];
  __shared__ float wadb[128];
  __shared__ float edsh[64];

  // --- was/wad: (W·a_src)[k], (W·a_dst)[k]  (fp32, 128 threads each) ---
  {
    const int k = t & 127;
    const float* wrow = W + ((size_t)hh * 128 + k) * 64;
    const float* av = a + hh * 128 + ((t >> 7) << 6);
    float s = 0.f;
#pragma unroll
    for (int o = 0; o < 16; ++o) {
      const float4 wv = *(const float4*)(wrow + o * 4);
      const float4 av4 = *(const float4*)(av + o * 4);
      s += wv.x * av4.x + wv.y * av4.y + wv.z * av4.z + wv.w * av4.w;
    }
    if (t < 128) wasb[k] = s; else wadb[k] = s;
  }

  // --- stage WT[f][k] f16, 16B-chunk XOR swizzle: slot = (k>>3) ^ (f&15) ---
  {
    const int k = t >> 1, fh = (t & 1) * 32;
    const float* wsrc = W + ((size_t)hh * 128 + k) * 64 + fh;
    const int chunk = k >> 3, within = k & 7;
#pragma unroll
    for (int i = 0; i < 8; ++i) {
      const float4 v = *(const float4*)(wsrc + i * 4);
      const _Float16 f4[4] = {(_Float16)v.x, (_Float16)v.y,
                              (_Float16)v.z, (_Float16)v.w};
#pragma unroll
      for (int u = 0; u < 4; ++u) {
        const int f = fh + i * 4 + u;
        WT[f * 128 + ((chunk ^ (f & 15)) << 3) + within] = f4[u];
      }
    }
  }

  __syncthreads();   // wasb/wadb ready (also orders WT writes)

  // --- stage Xs[n][k] f16 (swizzled) + fp32 e-partials ---
  {
    const int r = t >> 2, cq = t & 3;   // row r (0..63), col-quarter cq*32
    const float* hsrc = h + ((size_t)(b * NN + n0 + r)) * FIN + cq * 32;
    float es = 0.f, ed = 0.f;
#pragma unroll
    for (int i = 0; i < 8; ++i) {
      const float4 v = *(const float4*)(hsrc + i * 4);
      const float4 ws = *(const float4*)&wasb[cq * 32 + i * 4];
      const float4 wd = *(const float4*)&wadb[cq * 32 + i * 4];
      es += v.x * ws.x + v.y * ws.y + v.z * ws.z + v.w * ws.w;
      ed += v.x * wd.x + v.y * wd.y + v.z * wd.z + v.w * wd.w;
      PK4 pk;
      pk.f[0] = (_Float16)v.x; pk.f[1] = (_Float16)v.y;
      pk.f[2] = (_Float16)v.z; pk.f[3] = (_Float16)v.w;
      const int chunk = cq * 4 + (i >> 1);
      *(uint2*)&Xs[r * 128 + ((chunk ^ (r & 15)) << 3) + (i & 1) * 4] = pk.u;
    }
    es += __shfl_xor(es, 1, 64); es += __shfl_xor(es, 2, 64);
    ed += __shfl_xor(ed, 1, 64); ed += __shfl_xor(ed, 2, 64);
    if (cq == 0) {
      const float edl = ed * LOG2E;
      esrcT[(size_t)(n0 + r) * CC + c] = es * LOG2E;
      edst[(size_t)c * NN + n0 + r]    = edl;
      edsh[r] = edl;
    }
  }

  __syncthreads();   // Xs + edsh ready

  // --- per-(c,tile) edst max -> gpart (wave 0) ---
  if (t < 64) {
    float v = edsh[t];
#pragma unroll
    for (int off = 1; off < 64; off <<= 1) v = fmaxf(v, __shfl_xor(v, off, 64));
    if (t == 0) gpart[c * 32 + nt] = v;
  }

  // --- MFMA: wave w owns rows n0 + w*16 + [0,16), all 64 f ---
  floatx4 acc[4];
#pragma unroll
  for (int ft = 0; ft < 4; ++ft) acc[ft] = floatx4{0.f, 0.f, 0.f, 0.f};

  half8 afrag[4];
#pragma unroll
  for (int ks = 0; ks < 4; ++ks) {
    const int slot = (ks * 4 + q) ^ r16;
    afrag[ks] = *(const half8*)&Xs[(w * 16 + r16) * 128 + (slot << 3)];
  }
#pragma unroll
  for (int ks = 0; ks < 4; ++ks) {
#pragma unroll
    for (int ft = 0; ft < 4; ++ft) {
      const int fr = ft * 16 + r16;
      const int slot = (ks * 4 + q) ^ (fr & 15);
      const half8 bfrag = *(const half8*)&WT[fr * 128 + (slot << 3)];
      acc[ft] = __builtin_amdgcn_mfma_f32_16x16x32_f16(afrag[ks], bfrag,
                                                       acc[ft], 0, 0, 0);
    }
  }

  // --- epilogue: C col=lane&15 (=f within tile), row=q*4+reg (=n) ---
#pragma unroll
  for (int ft = 0; ft < 4; ++ft) {
    PK4 pk;
#pragma unroll
    for (int x = 0; x < 4; ++x) pk.f[x] = (_Float16)acc[ft][x];
    const int fcol = ft * 16 + r16;
    const int n = n0 + w * 16 + q * 4;
    *(uint2*)(htT + ((size_t)c * FO + fcol) * NN + n) = pk.u;
  }
}

// ---------------------------------------------------------------------------
// K3: O = softmax(P)·V, P built in A-fragment registers. 1024 thr = 16 waves:
// 4 row-groups x 4 k-groups. XCD-pinned c-major block swizzle: all 32 blocks
// of a c land on XCD c&7 -> V (256 KB) is read once per XCD into L2 and then
// L2-hit for the other 31 blocks (was 128 MB of cold L3/HBM traffic per iter
// because the workspace poison evicts everything). 8 steps x 256-n windows
// (half the barriers of R4). V double-buffered (2x32 KB) via global_load_lds
// + XOR swizzle; edst staged once in LDS; rm = lrelu(em + gmax_c) upper
// bound; row sums via ones-MFMA. grid 512 x 1024.
// ---------------------------------------------------------------------------
__global__ __launch_bounds__(1024, 8) void gat_k3_pv(
    const _Float16* __restrict__ htT, const float* __restrict__ esrcT,
    const float* __restrict__ edst, const unsigned* __restrict__ adjbits,
    const float* __restrict__ gpart, float* __restrict__ out) {
  const int blk0 = blockIdx.x;
  const int c  = (blk0 & 7) | (((blk0 >> 3) & 1) << 3);  // XCD pin: blk%8==c&7
  const int m0 = (blk0 >> 4) * 64;
  const int b = c >> 2, hh = c & 3;
  const int t = threadIdx.x;
  const int w = t >> 6;        // 0..15
  const int kg = w >> 2;       // k-group 0..3 (64-wide k-window per step)
  const int wl = w & 3;        // row-group
  const int lane = t & 63;
  const int q = lane >> 4, r16 = lane & 15;
  const int row = m0 + wl * 16 + r16;

  // LDS map: [0,65536) Vt double buffer (2x32 KB); [65536,73728) edsF;
  // [73728,73744) gmax. Epilogue reduce buffer (64.5 KB) reuses Vt region.
  __shared__ __align__(16) char smem[73744];
  _Float16* Vt = (_Float16*)smem;
  float* edsF = (float*)(smem + 65536);
  float* gmaxp = (float*)(smem + 73728);
  float* abuf = (float*)smem;

  const unsigned* abrow = adjbits + (size_t)row * 64;
  const _Float16* vsrc = htT + (size_t)c * FO * NN;

  // staging map: 2048 x 16B chunks per buffer ([64f][256n] f16). chunk idx ->
  // f = idx>>5, slot sg = idx&31; linear LDS dest, pre-swizzled global src:
  // slot sg of row f holds global n-octet sg^(f&31).
  const int f0 = t >> 5, sg0 = t & 31;
  const int f1 = (t + 1024) >> 5;
  const size_t goff0 = (size_t)f0 * NN + (size_t)((sg0 ^ (f0 & 31)) * 8);
  const size_t goff1 = (size_t)f1 * NN + (size_t)((sg0 ^ (f1 & 31)) * 8);

#define STAGE(BUF, NBASE)                                                      \
  do {                                                                         \
    __builtin_amdgcn_global_load_lds(                                          \
        (const __attribute__((address_space(1))) void*)(vsrc + goff0 + (NBASE)),\
        (__attribute__((address_space(3))) void*)(smem + (BUF)*32768 + t*16),  \
        16, 0, 0);                                                             \
    __builtin_amdgcn_global_load_lds(                                          \
        (const __attribute__((address_space(1))) void*)(vsrc + goff1 + (NBASE)),\
        (__attribute__((address_space(3))) void*)(smem + (BUF)*32768 + (t+1024)*16),\
        16, 0, 0);                                                             \
  } while (0)

  STAGE(0, 0);

  // prologue: stage edc -> LDS (8 KB), reduce gpart -> gmax
  *(float2*)&edsF[t * 2] = *(const float2*)(edst + (size_t)c * NN + t * 2);
  {
    float gv = (t < 32) ? gpart[c * 32 + t] : -3.0e38f;
    if (t < 64) {
#pragma unroll
      for (int off = 1; off < 32; off <<= 1)
        gv = fmaxf(gv, __shfl_xor(gv, off, 64));
      if (t == 0) *gmaxp = gv;
    }
  }
  __syncthreads();   // edsF + gmax visible (also drains STAGE(0))

  const float em = esrcT[(size_t)row * CC + c];
  const float gm = *gmaxp;
  const float s0 = em + gm;
  const float rm = (s0 >= 0.f) ? s0 : ALPHA * s0;   // upper bound on row max
  const float em1 = em - rm;
  const float em2 = fmaf(ALPHA, em, -rm);

  floatx4 acc[4];
#pragma unroll
  for (int ft = 0; ft < 4; ++ft) acc[ft] = floatx4{0.f, 0.f, 0.f, 0.f};
  floatx4 accs = floatx4{0.f, 0.f, 0.f, 0.f};

  half8 ones;
#pragma unroll
  for (int k = 0; k < 8; ++k) ones[k] = (_Float16)1.0f;

  for (int step = 0; step < 8; ++step) {
    const int nbase = step * 256 + kg * 64;  // this k-group's 64-wide window
    const uint2 bw = *(const uint2*)&abrow[step * 8 + kg * 2];

    // ---- build both 32-wide A-fragments (reads edsF only; LDS, static)
    half8 afrag0, afrag1;
#pragma unroll
    for (int h2 = 0; h2 < 2; ++h2) {
      const int nb = nbase + h2 * 32 + q * 8;
      const float4 ea = *(const float4*)&edsF[nb];
      const float4 eb = *(const float4*)&edsF[nb + 4];
      const float xs[8] = {ea.x, ea.y, ea.z, ea.w, eb.x, eb.y, eb.z, eb.w};
      const unsigned bits = ((h2 == 0) ? bw.x : bw.y) >> (q * 8);
      half8 af;
#pragma unroll
      for (int k = 0; k < 8; ++k) {
        const float t1 = em1 + xs[k];
        const float t2 = fmaf(ALPHA, xs[k], em2);
        float tt = fmaxf(t1, t2);                 // lrelu(em+x)-rm (log2 dom)
        tt = ((bits >> k) & 1u) ? tt : -3.0e38f;  // masked -> exp2 -> 0
        af[k] = (_Float16)fast_exp2(tt);
      }
      if (h2 == 0) afrag0 = af; else afrag1 = af;
    }

    // barrier drains vmcnt: current buffer's DMA complete everywhere
    __syncthreads();
    if (step + 1 < 8) STAGE((step + 1) & 1, (step + 1) * 256);

    // ---- MFMA from swizzled LDS V tile (+ ones-MFMA row sums)
    const int bufo = (step & 1) * 16384;  // f16 elements
    accs = __builtin_amdgcn_mfma_f32_16x16x32_f16(afrag0, ones, accs, 0, 0, 0);
#pragma unroll
    for (int ft = 0; ft < 4; ++ft) {
      const int fr = ft * 16 + r16;
      const int oct = kg * 8 + q;
      const half8 bfrag =
          *(const half8*)&Vt[bufo + fr * 256 + ((oct ^ (fr & 31)) << 3)];
      acc[ft] = __builtin_amdgcn_mfma_f32_16x16x32_f16(afrag0, bfrag,
                                                       acc[ft], 0, 0, 0);
    }
    accs = __builtin_amdgcn_mfma_f32_16x16x32_f16(afrag1, ones, accs, 0, 0, 0);
#pragma unroll
    for (int ft = 0; ft < 4; ++ft) {
      const int fr = ft * 16 + r16;
      const int oct = kg * 8 + 4 + q;
      const half8 bfrag =
          *(const half8*)&Vt[bufo + fr * 256 + ((oct ^ (fr & 31)) << 3)];
      acc[ft] = __builtin_amdgcn_mfma_f32_16x16x32_f16(afrag1, bfrag,
                                                       acc[ft], 0, 0, 0);
    }
  }

  // ---- 4-way k-group reduction through LDS (single shot, stride 21)
  __syncthreads();
  if (kg >= 1) {
    const int base = ((kg - 1) * 256 + (t & 255)) * 21;
#pragma unroll
    for (int ft = 0; ft < 4; ++ft)
#pragma unroll
      for (int x = 0; x < 4; ++x) abuf[base + ft * 4 + x] = acc[ft][x];
#pragma unroll
    for (int x = 0; x < 4; ++x) abuf[base + 16 + x] = accs[x];
  }
  __syncthreads();
  if (kg == 0) {
#pragma unroll
    for (int g = 0; g < 3; ++g) {
      const int base = (g * 256 + t) * 21;
#pragma unroll
      for (int ft = 0; ft < 4; ++ft)
#pragma unroll
        for (int x = 0; x < 4; ++x) acc[ft][x] += abuf[base + ft * 4 + x];
#pragma unroll
      for (int x = 0; x < 4; ++x) accs[x] += abuf[base + 16 + x];
    }
    // ---- epilogue: C layout col=lane&15, row=q*4+reg; accs[x] = row sum
#pragma unroll
    for (int x = 0; x < 4; ++x) {
      const float rinv = 1.0f / accs[x];
      const int mrow = m0 + wl * 16 + q * 4 + x;
      float* op = out + ((size_t)b * NN + mrow) * 256 + hh * 64;
#pragma unroll
      for (int ft = 0; ft < 4; ++ft) op[ft * 16 + r16] = acc[ft][x] * rinv;
    }
  }
#undef STAGE
}

// ---------------------------------------------------------------------------
extern "C" void kernel_launch(void* const* d_in, const int* in_sizes, int n_in,
                              void* d_out, int out_size, void* d_ws, size_t ws_size,
                              hipStream_t stream) {
  const float* h   = (const float*)d_in[0];   // (4,2048,128)
  const float* adj = (const float*)d_in[1];   // (2048,2048)
  const float* W   = (const float*)d_in[2];   // (4,128,64)
  const float* a   = (const float*)d_in[3];   // (4,128,1)
  float* out = (float*)d_out;                  // (4,2048,256)

  char* ws = (char*)d_ws;
  _Float16* htT   = (_Float16*)(ws);                         // 4 MB
  float* esrcT    = (float*)(ws + 4 * 1024 * 1024);           // 128 KB [n][c]
  float* edst     = (float*)(ws + 4 * 1024 * 1024 + 131072);  // 128 KB [c][n]
  unsigned* abits = (unsigned*)(ws + 4 * 1024 * 1024 + 2 * 131072);        // 512 KB
  float* gpart    = (float*)(ws + 4 * 1024 * 1024 + 2 * 131072 + 524288);  // 2 KB [c][32]

  gat_k12<<<dim3(1024), dim3(256), 0, stream>>>(h, W, a, adj, htT, esrcT,
                                                edst, gpart, abits);
  gat_k3_pv<<<dim3(CC * (NN / 64)), dim3(1024), 0, stream>>>(htT, esrcT, edst,
                                                             abits, gpart, out);
}

// Round 7
// 110.376 us; speedup vs baseline: 1.0303x; 1.0303x over previous
//
#include <hip/hip_runtime.h>

#define ALPHA 0.2f
#define LOG2E 1.44269504088896340736f

constexpr int BB  = 4;
constexpr int NN  = 2048;
constexpr int FIN = 128;
constexpr int FO  = 64;
constexpr int HH  = 4;
constexpr int CC  = BB * HH;   // 16 (b,h) combos

using half8   = __attribute__((ext_vector_type(8))) _Float16;
using floatx4 = __attribute__((ext_vector_type(4))) float;

__device__ __forceinline__ float fast_exp2(float x) {
#if __has_builtin(__builtin_amdgcn_exp2f)
  return __builtin_amdgcn_exp2f(x);
#else
  return exp2f(x);
#endif
}

union PK4 { _Float16 f[4]; uint2 u; };

// ---------------------------------------------------------------------------
// K12: two block roles in one kernel (verbatim from R5 -- verified).
//  blocks 0..511   : adjacency bitpack.
//  blocks 512..1023: projection ht = h·W via f16 MFMA; esrc/edst fp32-exact
//                    via h·(W·a) (log2e-scaled); gpart tile-max. XCD-pinned.
// grid 1024 x 256.
// ---------------------------------------------------------------------------
__global__ __launch_bounds__(256) void gat_k12(
    const float* __restrict__ h, const float* __restrict__ W,
    const float* __restrict__ a, const float* __restrict__ adj,
    _Float16* __restrict__ htT, float* __restrict__ esrcT,
    float* __restrict__ edst, float* __restrict__ gpart,
    unsigned* __restrict__ adjbits) {
  const int blk = blockIdx.x;
  const int t = threadIdx.x;
  const int w = t >> 6, lane = t & 63;

  if (blk < 512) {
    const int m = blk * 4 + w;
    float areg[32];
    const float* arow = adj + (size_t)m * NN;
#pragma unroll
    for (int j = 0; j < 32; ++j) areg[j] = arow[j * 64 + lane];
#pragma unroll
    for (int j = 0; j < 32; ++j) {
      const unsigned long long mask = __ballot(areg[j] != 0.f);
      if (lane == 0) {
        adjbits[m * 64 + j * 2 + 0] = (unsigned)mask;
        adjbits[m * 64 + j * 2 + 1] = (unsigned)(mask >> 32);
      }
    }
    return;
  }

  const int pb = blk - 512;
  const int c  = (pb & 7) | (((pb >> 3) & 1) << 3);  // XCD pin: pb%8 == c&7
  const int nt = pb >> 4;
  const int n0 = nt * 64;
  const int b = c >> 2, hh = c & 3;
  const int q = lane >> 4, r16 = lane & 15;

  __shared__ __align__(16) _Float16 Xs[64 * 128];
  __shared__ __align__(16) _Float16 WT[64 * 128];
  __shared__ float wasb[128];
  __shared__ float wadb[128];
  __shared__ float edsh[64];

  {
    const int k = t & 127;
    const float* wrow = W + ((size_t)hh * 128 + k) * 64;
    const float* av = a + hh * 128 + ((t >> 7) << 6);
    float s = 0.f;
#pragma unroll
    for (int o = 0; o < 16; ++o) {
      const float4 wv = *(const float4*)(wrow + o * 4);
      const float4 av4 = *(const float4*)(av + o * 4);
      s += wv.x * av4.x + wv.y * av4.y + wv.z * av4.z + wv.w * av4.w;
    }
    if (t < 128) wasb[k] = s; else wadb[k] = s;
  }

  {
    const int k = t >> 1, fh = (t & 1) * 32;
    const float* wsrc = W + ((size_t)hh * 128 + k) * 64 + fh;
    const int chunk = k >> 3, within = k & 7;
#pragma unroll
    for (int i = 0; i < 8; ++i) {
      const float4 v = *(const float4*)(wsrc + i * 4);
      const _Float16 f4[4] = {(_Float16)v.x, (_Float16)v.y,
                              (_Float16)v.z, (_Float16)v.w};
#pragma unroll
      for (int u = 0; u < 4; ++u) {
        const int f = fh + i * 4 + u;
        WT[f * 128 + ((chunk ^ (f & 15)) << 3) + within] = f4[u];
      }
    }
  }

  __syncthreads();

  {
    const int r = t >> 2, cq = t & 3;
    const float* hsrc = h + ((size_t)(b * NN + n0 + r)) * FIN + cq * 32;
    float es = 0.f, ed = 0.f;
#pragma unroll
    for (int i = 0; i < 8; ++i) {
      const float4 v = *(const float4*)(hsrc + i * 4);
      const float4 ws = *(const float4*)&wasb[cq * 32 + i * 4];
      const float4 wd = *(const float4*)&wadb[cq * 32 + i * 4];
      es += v.x * ws.x + v.y * ws.y + v.z * ws.z + v.w * ws.w;
      ed += v.x * wd.x + v.y * wd.y + v.z * wd.z + v.w * wd.w;
      PK4 pk;
      pk.f[0] = (_Float16)v.x; pk.f[1] = (_Float16)v.y;
      pk.f[2] = (_Float16)v.z; pk.f[3] = (_Float16)v.w;
      const int chunk = cq * 4 + (i >> 1);
      *(uint2*)&Xs[r * 128 + ((chunk ^ (r & 15)) << 3) + (i & 1) * 4] = pk.u;
    }
    es += __shfl_xor(es, 1, 64); es += __shfl_xor(es, 2, 64);
    ed += __shfl_xor(ed, 1, 64); ed += __shfl_xor(ed, 2, 64);
    if (cq == 0) {
      const float edl = ed * LOG2E;
      esrcT[(size_t)(n0 + r) * CC + c] = es * LOG2E;
      edst[(size_t)c * NN + n0 + r]    = edl;
      edsh[r] = edl;
    }
  }

  __syncthreads();

  if (t < 64) {
    float v = edsh[t];
#pragma unroll
    for (int off = 1; off < 64; off <<= 1) v = fmaxf(v, __shfl_xor(v, off, 64));
    if (t == 0) gpart[c * 32 + nt] = v;
  }

  floatx4 acc[4];
#pragma unroll
  for (int ft = 0; ft < 4; ++ft) acc[ft] = floatx4{0.f, 0.f, 0.f, 0.f};

  half8 afrag[4];
#pragma unroll
  for (int ks = 0; ks < 4; ++ks) {
    const int slot = (ks * 4 + q) ^ r16;
    afrag[ks] = *(const half8*)&Xs[(w * 16 + r16) * 128 + (slot << 3)];
  }
#pragma unroll
  for (int ks = 0; ks < 4; ++ks) {
#pragma unroll
    for (int ft = 0; ft < 4; ++ft) {
      const int fr = ft * 16 + r16;
      const int slot = (ks * 4 + q) ^ (fr & 15);
      const half8 bfrag = *(const half8*)&WT[fr * 128 + (slot << 3)];
      acc[ft] = __builtin_amdgcn_mfma_f32_16x16x32_f16(afrag[ks], bfrag,
                                                       acc[ft], 0, 0, 0);
    }
  }

#pragma unroll
  for (int ft = 0; ft < 4; ++ft) {
    PK4 pk;
#pragma unroll
    for (int x = 0; x < 4; ++x) pk.f[x] = (_Float16)acc[ft][x];
    const int fcol = ft * 16 + r16;
    const int n = n0 + w * 16 + q * 4;
    *(uint2*)(htT + ((size_t)c * FO + fcol) * NN + n) = pk.u;
  }
}

// ---------------------------------------------------------------------------
// K3: O = softmax(P)·V with T3/T4 deep pipeline. 16 waves = 4 row-groups x
// 4 k-groups. 16 steps x 128-n windows; V staged in 3 x 16 KB buffers via
// global_load_lds + XOR swizzle, depth-2 prefetch; per-step sync is
// s_waitcnt vmcnt(1) lgkmcnt(0) + RAW s_barrier (newest stage load stays in
// flight across the barrier -- never drain to 0). NO other VMEM in the loop:
// adjbits rows (16 KB) + edst (8 KB) staged to LDS in prologue; em/gpart
// hoisted. rm = lrelu(em+gmax_c) upper bound; ones-MFMA row sums; 4-way
// k-reduce in LDS. grid 512 x 1024, 2 blocks/CU.
// ---------------------------------------------------------------------------
__global__ __launch_bounds__(1024, 8) void gat_k3_pv(
    const _Float16* __restrict__ htT, const float* __restrict__ esrcT,
    const float* __restrict__ edst, const unsigned* __restrict__ adjbits,
    const float* __restrict__ gpart, float* __restrict__ out) {
  const int blk0 = blockIdx.x;
  const int c  = (blk0 & 7) | (((blk0 >> 3) & 1) << 3);  // XCD pin
  const int m0 = (blk0 >> 4) * 64;
  const int b = c >> 2, hh = c & 3;
  const int t = threadIdx.x;
  const int w = t >> 6;        // 0..15
  const int kg = w >> 2;       // k-group 0..3 (32-wide window per step)
  const int wl = w & 3;        // row-group
  const int lane = t & 63;
  const int q = lane >> 4, r16 = lane & 15;
  const int row = m0 + wl * 16 + r16;
  const int rl  = wl * 16 + r16;     // row-local 0..63

  // LDS: [0,49152) Vt 3x16KB; [49152,57344) edsF; [57344,73728) abL;
  // [73728,73732) gmax. Epilogue abuf (64.5 KB) reuses [0,...).
  __shared__ __align__(16) char smem[73744];
  _Float16* Vt   = (_Float16*)smem;
  float* edsF    = (float*)(smem + 49152);
  unsigned* abL  = (unsigned*)(smem + 57344);
  float* gmaxp   = (float*)(smem + 73728);
  float* abuf    = (float*)smem;

  const _Float16* vsrc = htT + (size_t)c * FO * NN;

  // staging map: 1024 x 16B chunks per buffer ([64f][128n] f16); linear LDS
  // dest, pre-swizzled global src: slot sg of row f holds n-octet sg^(f&15).
  const int f0 = t >> 4, sg0 = t & 15;
  const size_t goff0 = (size_t)f0 * NN + (size_t)((sg0 ^ (f0 & 15)) * 8);

#define STAGE(BUF, NBASE)                                                      \
  __builtin_amdgcn_global_load_lds(                                            \
      (const __attribute__((address_space(1))) void*)(vsrc + goff0 + (NBASE)), \
      (__attribute__((address_space(3))) void*)(smem + (BUF)*16384 + t*16),    \
      16, 0, 0)

  // ---------------- prologue: hoist ALL loop-carried VMEM ----------------
  const float em = esrcT[(size_t)row * CC + c];
  const float2 edv = *(const float2*)(edst + (size_t)c * NN + t * 2);
  const uint4 abv = *(const uint4*)&adjbits[(size_t)(m0 + (t >> 4)) * 64 +
                                            (t & 15) * 4];
  float gv = (t < 32) ? gpart[c * 32 + t] : -3.0e38f;

  *(float2*)&edsF[t * 2] = edv;
  *(uint4*)&abL[(t >> 4) * 64 + (t & 15) * 4] = abv;
  if (t < 64) {
#pragma unroll
    for (int off = 1; off < 32; off <<= 1)
      gv = fmaxf(gv, __shfl_xor(gv, off, 64));
    if (t == 0) *gmaxp = gv;
  }
  __syncthreads();   // edsF + abL + gmax visible; all prologue VMEM drained

  const float gm = *gmaxp;
  const float s0 = em + gm;
  const float rm = (s0 >= 0.f) ? s0 : ALPHA * s0;   // upper bound on row max
  const float em1 = em - rm;
  const float em2 = fmaf(ALPHA, em, -rm);

  floatx4 acc[4];
#pragma unroll
  for (int ft = 0; ft < 4; ++ft) acc[ft] = floatx4{0.f, 0.f, 0.f, 0.f};
  floatx4 accs = floatx4{0.f, 0.f, 0.f, 0.f};

  half8 ones;
#pragma unroll
  for (int k = 0; k < 8; ++k) ones[k] = (_Float16)1.0f;

  STAGE(0, 0);
  STAGE(1, 128);

#pragma unroll
  for (int step = 0; step < 16; ++step) {
    const int bufs = step % 3;
    // ---- build A-fragment (LDS-only reads: abL broadcast + edsF broadcast)
    const unsigned bits = abL[rl * 64 + step * 4 + kg] >> (q * 8);
    const int nb = step * 128 + kg * 32 + q * 8;
    const float4 ea = *(const float4*)&edsF[nb];
    const float4 eb = *(const float4*)&edsF[nb + 4];
    const float xs[8] = {ea.x, ea.y, ea.z, ea.w, eb.x, eb.y, eb.z, eb.w};
    half8 afrag;
#pragma unroll
    for (int k = 0; k < 8; ++k) {
      const float t1 = em1 + xs[k];
      const float t2 = fmaf(ALPHA, xs[k], em2);
      float tt = fmaxf(t1, t2);                 // lrelu(em+x)-rm (log2 dom)
      tt = ((bits >> k) & 1u) ? tt : -3.0e38f;  // masked -> exp2 -> 0
      afrag[k] = (_Float16)fast_exp2(tt);
    }

    // ---- counted-vmcnt barrier: buf[step] ready everywhere; the newest
    // stage load (step+1) stays in flight across the barrier (T4).
    if (step < 15) {
      asm volatile("s_waitcnt vmcnt(1) lgkmcnt(0)" ::: "memory");
    } else {
      asm volatile("s_waitcnt vmcnt(0) lgkmcnt(0)" ::: "memory");
    }
    __builtin_amdgcn_s_barrier();
    asm volatile("" ::: "memory");

    // ---- depth-2 prefetch (overwrites buf[(step-1)%3], safe past barrier)
    if (step <= 13) STAGE((step + 2) % 3, (step + 2) * 128);

    // ---- MFMA from swizzled LDS V tile (+ ones-MFMA row sums)
    const int bufo = bufs * 8192;  // f16 elements
    accs = __builtin_amdgcn_mfma_f32_16x16x32_f16(afrag, ones, accs, 0, 0, 0);
#pragma unroll
    for (int ft = 0; ft < 4; ++ft) {
      const int fr = ft * 16 + r16;
      const int oct = kg * 4 + q;
      const half8 bfrag =
          *(const half8*)&Vt[bufo + fr * 128 + ((oct ^ (fr & 15)) << 3)];
      acc[ft] = __builtin_amdgcn_mfma_f32_16x16x32_f16(afrag, bfrag,
                                                       acc[ft], 0, 0, 0);
    }
  }

  // ---- 4-way k-group reduction through LDS (stride 21)
  __syncthreads();
  if (kg >= 1) {
    const int base = ((kg - 1) * 256 + (t & 255)) * 21;
#pragma unroll
    for (int ft = 0; ft < 4; ++ft)
#pragma unroll
      for (int x = 0; x < 4; ++x) abuf[base + ft * 4 + x] = acc[ft][x];
#pragma unroll
    for (int x = 0; x < 4; ++x) abuf[base + 16 + x] = accs[x];
  }
  __syncthreads();
  if (kg == 0) {
#pragma unroll
    for (int g = 0; g < 3; ++g) {
      const int base = (g * 256 + t) * 21;
#pragma unroll
      for (int ft = 0; ft < 4; ++ft)
#pragma unroll
        for (int x = 0; x < 4; ++x) acc[ft][x] += abuf[base + ft * 4 + x];
#pragma unroll
      for (int x = 0; x < 4; ++x) accs[x] += abuf[base + 16 + x];
    }
    // ---- epilogue: C layout col=lane&15, row=q*4+reg; accs[x] = row sum
#pragma unroll
    for (int x = 0; x < 4; ++x) {
      const float rinv = 1.0f / accs[x];
      const int mrow = m0 + wl * 16 + q * 4 + x;
      float* op = out + ((size_t)b * NN + mrow) * 256 + hh * 64;
#pragma unroll
      for (int ft = 0; ft < 4; ++ft) op[ft * 16 + r16] = acc[ft][x] * rinv;
    }
  }
#undef STAGE
}

// ---------------------------------------------------------------------------
extern "C" void kernel_launch(void* const* d_in, const int* in_sizes, int n_in,
                              void* d_out, int out_size, void* d_ws, size_t ws_size,
                              hipStream_t stream) {
  const float* h   = (const float*)d_in[0];   // (4,2048,128)
  const float* adj = (const float*)d_in[1];   // (2048,2048)
  const float* W   = (const float*)d_in[2];   // (4,128,64)
  const float* a   = (const float*)d_in[3];   // (4,128,1)
  float* out = (float*)d_out;                  // (4,2048,256)

  char* ws = (char*)d_ws;
  _Float16* htT   = (_Float16*)(ws);                         // 4 MB
  float* esrcT    = (float*)(ws + 4 * 1024 * 1024);           // 128 KB [n][c]
  float* edst     = (float*)(ws + 4 * 1024 * 1024 + 131072);  // 128 KB [c][n]
  unsigned* abits = (unsigned*)(ws + 4 * 1024 * 1024 + 2 * 131072);        // 512 KB
  float* gpart    = (float*)(ws + 4 * 1024 * 1024 + 2 * 131072 + 524288);  // 2 KB [c][32]

  gat_k12<<<dim3(1024), dim3(256), 0, stream>>>(h, W, a, adj, htT, esrcT,
                                                edst, gpart, abits);
  gat_k3_pv<<<dim3(CC * (NN / 64)), dim3(1024), 0, stream>>>(htT, esrcT, edst,
                                                             abits, gpart, out);
}

// Round 8
// 107.184 us; speedup vs baseline: 1.0610x; 1.0298x over previous
//
#include <hip/hip_runtime.h>

#define ALPHA 0.2f
#define LOG2E 1.44269504088896340736f

constexpr int BB  = 4;
constexpr int NN  = 2048;
constexpr int FIN = 128;
constexpr int FO  = 64;
constexpr int HH  = 4;
constexpr int CC  = BB * HH;   // 16 (b,h) combos

using half8   = __attribute__((ext_vector_type(8))) _Float16;
using floatx4 = __attribute__((ext_vector_type(4))) float;

__device__ __forceinline__ float fast_exp2(float x) {
#if __has_builtin(__builtin_amdgcn_exp2f)
  return __builtin_amdgcn_exp2f(x);
#else
  return exp2f(x);
#endif
}

union PK4 { _Float16 f[4]; uint2 u; };

// ---------------------------------------------------------------------------
// K12: two block roles in one kernel (verbatim from R5 -- verified).
//  blocks 0..511   : adjacency bitpack.
//  blocks 512..1023: projection ht = h·W via f16 MFMA; esrc/edst fp32-exact
//                    via h·(W·a) (log2e-scaled); gpart tile-max. XCD-pinned.
// grid 1024 x 256.
// ---------------------------------------------------------------------------
__global__ __launch_bounds__(256) void gat_k12(
    const float* __restrict__ h, const float* __restrict__ W,
    const float* __restrict__ a, const float* __restrict__ adj,
    _Float16* __restrict__ htT, float* __restrict__ esrcT,
    float* __restrict__ edst, float* __restrict__ gpart,
    unsigned* __restrict__ adjbits) {
  const int blk = blockIdx.x;
  const int t = threadIdx.x;
  const int w = t >> 6, lane = t & 63;

  if (blk < 512) {
    const int m = blk * 4 + w;
    float areg[32];
    const float* arow = adj + (size_t)m * NN;
#pragma unroll
    for (int j = 0; j < 32; ++j) areg[j] = arow[j * 64 + lane];
#pragma unroll
    for (int j = 0; j < 32; ++j) {
      const unsigned long long mask = __ballot(areg[j] != 0.f);
      if (lane == 0) {
        adjbits[m * 64 + j * 2 + 0] = (unsigned)mask;
        adjbits[m * 64 + j * 2 + 1] = (unsigned)(mask >> 32);
      }
    }
    return;
  }

  const int pb = blk - 512;
  const int c  = (pb & 7) | (((pb >> 3) & 1) << 3);  // XCD pin: pb%8 == c&7
  const int nt = pb >> 4;
  const int n0 = nt * 64;
  const int b = c >> 2, hh = c & 3;
  const int q = lane >> 4, r16 = lane & 15;

  __shared__ __align__(16) _Float16 Xs[64 * 128];
  __shared__ __align__(16) _Float16 WT[64 * 128];
  __shared__ float wasb[128];
  __shared__ float wadb[128];
  __shared__ float edsh[64];

  {
    const int k = t & 127;
    const float* wrow = W + ((size_t)hh * 128 + k) * 64;
    const float* av = a + hh * 128 + ((t >> 7) << 6);
    float s = 0.f;
#pragma unroll
    for (int o = 0; o < 16; ++o) {
      const float4 wv = *(const float4*)(wrow + o * 4);
      const float4 av4 = *(const float4*)(av + o * 4);
      s += wv.x * av4.x + wv.y * av4.y + wv.z * av4.z + wv.w * av4.w;
    }
    if (t < 128) wasb[k] = s; else wadb[k] = s;
  }

  {
    const int k = t >> 1, fh = (t & 1) * 32;
    const float* wsrc = W + ((size_t)hh * 128 + k) * 64 + fh;
    const int chunk = k >> 3, within = k & 7;
#pragma unroll
    for (int i = 0; i < 8; ++i) {
      const float4 v = *(const float4*)(wsrc + i * 4);
      const _Float16 f4[4] = {(_Float16)v.x, (_Float16)v.y,
                              (_Float16)v.z, (_Float16)v.w};
#pragma unroll
      for (int u = 0; u < 4; ++u) {
        const int f = fh + i * 4 + u;
        WT[f * 128 + ((chunk ^ (f & 15)) << 3) + within] = f4[u];
      }
    }
  }

  __syncthreads();

  {
    const int r = t >> 2, cq = t & 3;
    const float* hsrc = h + ((size_t)(b * NN + n0 + r)) * FIN + cq * 32;
    float es = 0.f, ed = 0.f;
#pragma unroll
    for (int i = 0; i < 8; ++i) {
      const float4 v = *(const float4*)(hsrc + i * 4);
      const float4 ws = *(const float4*)&wasb[cq * 32 + i * 4];
      const float4 wd = *(const float4*)&wadb[cq * 32 + i * 4];
      es += v.x * ws.x + v.y * ws.y + v.z * ws.z + v.w * ws.w;
      ed += v.x * wd.x + v.y * wd.y + v.z * wd.z + v.w * wd.w;
      PK4 pk;
      pk.f[0] = (_Float16)v.x; pk.f[1] = (_Float16)v.y;
      pk.f[2] = (_Float16)v.z; pk.f[3] = (_Float16)v.w;
      const int chunk = cq * 4 + (i >> 1);
      *(uint2*)&Xs[r * 128 + ((chunk ^ (r & 15)) << 3) + (i & 1) * 4] = pk.u;
    }
    es += __shfl_xor(es, 1, 64); es += __shfl_xor(es, 2, 64);
    ed += __shfl_xor(ed, 1, 64); ed += __shfl_xor(ed, 2, 64);
    if (cq == 0) {
      const float edl = ed * LOG2E;
      esrcT[(size_t)(n0 + r) * CC + c] = es * LOG2E;
      edst[(size_t)c * NN + n0 + r]    = edl;
      edsh[r] = edl;
    }
  }

  __syncthreads();

  if (t < 64) {
    float v = edsh[t];
#pragma unroll
    for (int off = 1; off < 64; off <<= 1) v = fmaxf(v, __shfl_xor(v, off, 64));
    if (t == 0) gpart[c * 32 + nt] = v;
  }

  floatx4 acc[4];
#pragma unroll
  for (int ft = 0; ft < 4; ++ft) acc[ft] = floatx4{0.f, 0.f, 0.f, 0.f};

  half8 afrag[4];
#pragma unroll
  for (int ks = 0; ks < 4; ++ks) {
    const int slot = (ks * 4 + q) ^ r16;
    afrag[ks] = *(const half8*)&Xs[(w * 16 + r16) * 128 + (slot << 3)];
  }
#pragma unroll
  for (int ks = 0; ks < 4; ++ks) {
#pragma unroll
    for (int ft = 0; ft < 4; ++ft) {
      const int fr = ft * 16 + r16;
      const int slot = (ks * 4 + q) ^ (fr & 15);
      const half8 bfrag = *(const half8*)&WT[fr * 128 + (slot << 3)];
      acc[ft] = __builtin_amdgcn_mfma_f32_16x16x32_f16(afrag[ks], bfrag,
                                                       acc[ft], 0, 0, 0);
    }
  }

#pragma unroll
  for (int ft = 0; ft < 4; ++ft) {
    PK4 pk;
#pragma unroll
    for (int x = 0; x < 4; ++x) pk.f[x] = (_Float16)acc[ft][x];
    const int fcol = ft * 16 + r16;
    const int n = n0 + w * 16 + q * 4;
    *(uint2*)(htT + ((size_t)c * FO + fcol) * NN + n) = pk.u;
  }
}

// ---------------------------------------------------------------------------
// K3: O = softmax(P)·V with T3/T4 deep pipeline. 16 waves = 4 row-groups x
// 4 k-groups. 16 steps x 128-n windows; V staged in 3 x 16 KB buffers via
// global_load_lds + XOR swizzle, depth-2 prefetch; per-step sync is
// s_waitcnt vmcnt(1) lgkmcnt(0) + RAW s_barrier (never drain to 0). NO other
// VMEM in the loop: adjbits rows + edst staged to LDS in prologue. abL row
// stride = 68 words (was 64: every row hit bank 0 -> 16-way conflict; 68 ->
// 2-way, free). T5 setprio around the MFMA cluster (counted-vmcnt staggers
// waves -> role diversity). rm = lrelu(em+gmax_c) upper bound; ones-MFMA row
// sums; 4-way k-reduce in LDS. grid 512 x 1024, 2 blocks/CU.
// ---------------------------------------------------------------------------
__global__ __launch_bounds__(1024, 8) void gat_k3_pv(
    const _Float16* __restrict__ htT, const float* __restrict__ esrcT,
    const float* __restrict__ edst, const unsigned* __restrict__ adjbits,
    const float* __restrict__ gpart, float* __restrict__ out) {
  const int blk0 = blockIdx.x;
  const int c  = (blk0 & 7) | (((blk0 >> 3) & 1) << 3);  // XCD pin
  const int m0 = (blk0 >> 4) * 64;
  const int b = c >> 2, hh = c & 3;
  const int t = threadIdx.x;
  const int w = t >> 6;        // 0..15
  const int kg = w >> 2;       // k-group 0..3 (32-wide window per step)
  const int wl = w & 3;        // row-group
  const int lane = t & 63;
  const int q = lane >> 4, r16 = lane & 15;
  const int row = m0 + wl * 16 + r16;
  const int rl  = wl * 16 + r16;     // row-local 0..63

  // LDS: [0,49152) Vt 3x16KB; [49152,57344) edsF; [57344,74752) abL
  // (64 rows x 68 words); [74752,74756) gmax. Epilogue abuf reuses [0,..).
  __shared__ __align__(16) char smem[74768];
  _Float16* Vt   = (_Float16*)smem;
  float* edsF    = (float*)(smem + 49152);
  unsigned* abL  = (unsigned*)(smem + 57344);
  float* gmaxp   = (float*)(smem + 74752);
  float* abuf    = (float*)smem;

  const _Float16* vsrc = htT + (size_t)c * FO * NN;

  // staging map: 1024 x 16B chunks per buffer ([64f][128n] f16); linear LDS
  // dest, pre-swizzled global src: slot sg of row f holds n-octet sg^(f&15).
  const int f0 = t >> 4, sg0 = t & 15;
  const size_t goff0 = (size_t)f0 * NN + (size_t)((sg0 ^ (f0 & 15)) * 8);

#define STAGE(BUF, NBASE)                                                      \
  __builtin_amdgcn_global_load_lds(                                            \
      (const __attribute__((address_space(1))) void*)(vsrc + goff0 + (NBASE)), \
      (__attribute__((address_space(3))) void*)(smem + (BUF)*16384 + t*16),    \
      16, 0, 0)

  // ---------------- prologue: hoist ALL loop-carried VMEM ----------------
  const float em = esrcT[(size_t)row * CC + c];
  const float2 edv = *(const float2*)(edst + (size_t)c * NN + t * 2);
  const uint4 abv = *(const uint4*)&adjbits[(size_t)(m0 + (t >> 4)) * 64 +
                                            (t & 15) * 4];
  float gv = (t < 32) ? gpart[c * 32 + t] : -3.0e38f;

  *(float2*)&edsF[t * 2] = edv;
  *(uint4*)&abL[(t >> 4) * 68 + (t & 15) * 4] = abv;
  if (t < 64) {
#pragma unroll
    for (int off = 1; off < 32; off <<= 1)
      gv = fmaxf(gv, __shfl_xor(gv, off, 64));
    if (t == 0) *gmaxp = gv;
  }
  __syncthreads();   // edsF + abL + gmax visible; all prologue VMEM drained

  const float gm = *gmaxp;
  const float s0 = em + gm;
  const float rm = (s0 >= 0.f) ? s0 : ALPHA * s0;   // upper bound on row max
  const float em1 = em - rm;
  const float em2 = fmaf(ALPHA, em, -rm);

  floatx4 acc[4];
#pragma unroll
  for (int ft = 0; ft < 4; ++ft) acc[ft] = floatx4{0.f, 0.f, 0.f, 0.f};
  floatx4 accs = floatx4{0.f, 0.f, 0.f, 0.f};

  half8 ones;
#pragma unroll
  for (int k = 0; k < 8; ++k) ones[k] = (_Float16)1.0f;

  STAGE(0, 0);
  STAGE(1, 128);

#pragma unroll
  for (int step = 0; step < 16; ++step) {
    const int bufs = step % 3;
    // ---- build A-fragment (LDS-only reads: abL + edsF broadcast)
    const unsigned bits = abL[rl * 68 + step * 4 + kg] >> (q * 8);
    const int nb = step * 128 + kg * 32 + q * 8;
    const float4 ea = *(const float4*)&edsF[nb];
    const float4 eb = *(const float4*)&edsF[nb + 4];
    const float xs[8] = {ea.x, ea.y, ea.z, ea.w, eb.x, eb.y, eb.z, eb.w};
    half8 afrag;
#pragma unroll
    for (int k = 0; k < 8; ++k) {
      const float t1 = em1 + xs[k];
      const float t2 = fmaf(ALPHA, xs[k], em2);
      float tt = fmaxf(t1, t2);                 // lrelu(em+x)-rm (log2 dom)
      tt = ((bits >> k) & 1u) ? tt : -3.0e38f;  // masked -> exp2 -> 0
      afrag[k] = (_Float16)fast_exp2(tt);
    }

    // ---- counted-vmcnt barrier: buf[step] ready everywhere; the newest
    // stage load (step+1) stays in flight across the barrier (T4).
    if (step < 15) {
      asm volatile("s_waitcnt vmcnt(1) lgkmcnt(0)" ::: "memory");
    } else {
      asm volatile("s_waitcnt vmcnt(0) lgkmcnt(0)" ::: "memory");
    }
    __builtin_amdgcn_s_barrier();
    asm volatile("" ::: "memory");

    // ---- depth-2 prefetch (overwrites buf[(step-1)%3], safe past barrier)
    if (step <= 13) STAGE((step + 2) % 3, (step + 2) * 128);

    // ---- MFMA from swizzled LDS V tile (+ ones-MFMA row sums), T5-wrapped
    const int bufo = bufs * 8192;  // f16 elements
    __builtin_amdgcn_s_setprio(1);
    accs = __builtin_amdgcn_mfma_f32_16x16x32_f16(afrag, ones, accs, 0, 0, 0);
#pragma unroll
    for (int ft = 0; ft < 4; ++ft) {
      const int fr = ft * 16 + r16;
      const int oct = kg * 4 + q;
      const half8 bfrag =
          *(const half8*)&Vt[bufo + fr * 128 + ((oct ^ (fr & 15)) << 3)];
      acc[ft] = __builtin_amdgcn_mfma_f32_16x16x32_f16(afrag, bfrag,
                                                       acc[ft], 0, 0, 0);
    }
    __builtin_amdgcn_s_setprio(0);
  }

  // ---- 4-way k-group reduction through LDS (stride 21)
  __syncthreads();
  if (kg >= 1) {
    const int base = ((kg - 1) * 256 + (t & 255)) * 21;
#pragma unroll
    for (int ft = 0; ft < 4; ++ft)
#pragma unroll
      for (int x = 0; x < 4; ++x) abuf[base + ft * 4 + x] = acc[ft][x];
#pragma unroll
    for (int x = 0; x < 4; ++x) abuf[base + 16 + x] = accs[x];
  }
  __syncthreads();
  if (kg == 0) {
#pragma unroll
    for (int g = 0; g < 3; ++g) {
      const int base = (g * 256 + t) * 21;
#pragma unroll
      for (int ft = 0; ft < 4; ++ft)
#pragma unroll
        for (int x = 0; x < 4; ++x) acc[ft][x] += abuf[base + ft * 4 + x];
#pragma unroll
      for (int x = 0; x < 4; ++x) accs[x] += abuf[base + 16 + x];
    }
    // ---- epilogue: C layout col=lane&15, row=q*4+reg; accs[x] = row sum
#pragma unroll
    for (int x = 0; x < 4; ++x) {
      const float rinv = 1.0f / accs[x];
      const int mrow = m0 + wl * 16 + q * 4 + x;
      float* op = out + ((size_t)b * NN + mrow) * 256 + hh * 64;
#pragma unroll
      for (int ft = 0; ft < 4; ++ft) op[ft * 16 + r16] = acc[ft][x] * rinv;
    }
  }
#undef STAGE
}

// ---------------------------------------------------------------------------
extern "C" void kernel_launch(void* const* d_in, const int* in_sizes, int n_in,
                              void* d_out, int out_size, void* d_ws, size_t ws_size,
                              hipStream_t stream) {
  const float* h   = (const float*)d_in[0];   // (4,2048,128)
  const float* adj = (const float*)d_in[1];   // (2048,2048)
  const float* W   = (const float*)d_in[2];   // (4,128,64)
  const float* a   = (const float*)d_in[3];   // (4,128,1)
  float* out = (float*)d_out;                  // (4,2048,256)

  char* ws = (char*)d_ws;
  _Float16* htT   = (_Float16*)(ws);                         // 4 MB
  float* esrcT    = (float*)(ws + 4 * 1024 * 1024);           // 128 KB [n][c]
  float* edst     = (float*)(ws + 4 * 1024 * 1024 + 131072);  // 128 KB [c][n]
  unsigned* abits = (unsigned*)(ws + 4 * 1024 * 1024 + 2 * 131072);        // 512 KB
  float* gpart    = (float*)(ws + 4 * 1024 * 1024 + 2 * 131072 + 524288);  // 2 KB [c][32]

  gat_k12<<<dim3(1024), dim3(256), 0, stream>>>(h, W, a, adj, htT, esrcT,
                                                edst, gpart, abits);
  gat_k3_pv<<<dim3(CC * (NN / 64)), dim3(1024), 0, stream>>>(htT, esrcT, edst,
                                                             abits, gpart, out);
}